// Round 1
// baseline (244.346 us; speedup 1.0000x reference)
//
#include <hip/hip_runtime.h>

// KanLinear: out[b,o] = silu(x)@scale_base + bases@(spline_w*scale_spline)
// Round 10:
//  - kan_gemm_all rebuilt as 256x128-tile, 8-wave, double-buffered 2-phase
//    prefetch (T3 minimum-2-phase): STAGE(t+1) issued BEFORE compute(t),
//    one barrier per K-step. Staging (L2-BW ~1100cyc/K-step) now overlaps
//    MFMA (~1100cyc) instead of serializing -> predicted MfmaUtil 34->55%.
//  - BM=256 halves B re-staging per output element; grid 256 = 1 block/CU
//    (8 waves in-block provide the overlap, HK-style).
//  - fp8->bf16 phase chained through the same double buffer (no bubble).
//  - Same XOR swizzles / source-pre-swizzle, same accumulation order.
//  - kan_mix untouched (will surface in next round's counters).

#define BATCH 8192
#define IN_F  1024
#define OUT_F 1024
#define GRID_N 8
#define K2    (IN_F * GRID_N)          // spline K = 8192
#define KTOT  (IN_F + K2)              // 9216 (fallback path)

#define BM 128
#define BN 128
#define BK 64        // bf16 k-tile
#define BK8 128      // fp8 k-tile (bytes)

typedef __bf16 bf16x8 __attribute__((ext_vector_type(8)));
typedef float  f32x4  __attribute__((ext_vector_type(4)));
typedef int    int32x8 __attribute__((ext_vector_type(8)));

__device__ __forceinline__ void gl2lds16(const void* g, void* l) {
  __builtin_amdgcn_global_load_lds(
      (const __attribute__((address_space(1))) void*)g,
      (__attribute__((address_space(3))) void*)l, 16, 0, 0);
}

__device__ __forceinline__ void pack_fp8x8(const float* v, int& w0, int& w1) {
  w0 = 0; w1 = 0;
  w0 = __builtin_amdgcn_cvt_pk_fp8_f32(v[0], v[1], w0, false);
  w0 = __builtin_amdgcn_cvt_pk_fp8_f32(v[2], v[3], w0, true);
  w1 = __builtin_amdgcn_cvt_pk_fp8_f32(v[4], v[5], w1, false);
  w1 = __builtin_amdgcn_cvt_pk_fp8_f32(v[6], v[7], w1, true);
}

// ---------- launch 1: pure elementwise prep, all streams coalesced ----------
// blocks [0,256):      sbT[o][k] = (bf16)scale_base[k][o]  (LDS transpose)
// blocks [256,512):    spline-pack tile 64o x 512j with LDS-staged ss
// blocks [512,8704):   row b: sbA[b][k]=bf16(silu(x)), Ab8[b][i*8+g]=fp8(base)
__global__ __launch_bounds__(256)
void kan_mix(const float* __restrict__ x, const float* __restrict__ sb,
             const float* __restrict__ sw, const float* __restrict__ ss,
             const float* __restrict__ grid, const float* __restrict__ sigma,
             __bf16* __restrict__ sbT, unsigned char* __restrict__ wbt8,
             unsigned char* __restrict__ Ab8, __bf16* __restrict__ sbA) {
  const int t = threadIdx.x;
  const int bx = blockIdx.x;
  if (bx < 256) {
    // ---- sb transpose (64x64 f32 tiles) ----
    __shared__ float tile[64][65];
    const int o0 = (bx & 15) * 64, k0 = (bx >> 4) * 64;
    const int r = t >> 4, c4 = (t & 15) * 4;
    #pragma unroll
    for (int it = 0; it < 4; ++it) {
      const int k = k0 + r + it * 16;
      float4 v = *(const float4*)(sb + (size_t)k * OUT_F + o0 + c4);
      tile[r + it * 16][c4 + 0] = v.x; tile[r + it * 16][c4 + 1] = v.y;
      tile[r + it * 16][c4 + 2] = v.z; tile[r + it * 16][c4 + 3] = v.w;
    }
    __syncthreads();
    #pragma unroll
    for (int it = 0; it < 4; ++it) {
      const int ol = r + it * 16;
      union { __bf16 h[4]; uint2 q; } s;
      #pragma unroll
      for (int e = 0; e < 4; ++e) s.h[e] = (__bf16)tile[c4 + e][ol];
      *(uint2*)(sbT + (size_t)(o0 + ol) * IN_F + k0 + c4) = s.q;
    }
  } else if (bx < 512) {
    // ---- spline-pack: tile = o in [o0,o0+64), j in [j0,j0+512), i=j/8 ----
    __shared__ float tile[64][65];        // tile[i_local][o_local]
    const int sp = bx - 256;              // [0,256)
    const int o0 = (sp >> 4) * 64;
    const int j0 = (sp & 15) * 512;
    const int i0 = j0 >> 3;               // 64 i's per tile
    // stage ss[i0..i0+64)[o0..o0+64) coalesced (float4 per lane)
    const int r = t >> 4, c4 = (t & 15) * 4;
    #pragma unroll
    for (int it = 0; it < 4; ++it) {
      const int i = i0 + r + it * 16;
      float4 v = *(const float4*)(ss + (size_t)i * OUT_F + o0 + c4);
      tile[r + it * 16][c4 + 0] = v.x; tile[r + it * 16][c4 + 1] = v.y;
      tile[r + it * 16][c4 + 2] = v.z; tile[r + it * 16][c4 + 3] = v.w;
    }
    __syncthreads();
    // pack: pass p handles flat f = p*256+t over 4096 (o_l,i_l) pairs,
    // i_l fastest -> sw reads & wbt8 writes fully coalesced.
    #pragma unroll
    for (int p = 0; p < 16; ++p) {
      const int f = p * 256 + t;
      const int o_l = f >> 6, i_l = f & 63;
      const float sc = tile[i_l][o_l];
      const float* swp = sw + (size_t)(o0 + o_l) * K2 + j0 + i_l * 8;
      float4 a = *(const float4*)swp;
      float4 b = *(const float4*)(swp + 4);
      float vv[8] = {a.x * sc, a.y * sc, a.z * sc, a.w * sc,
                     b.x * sc, b.y * sc, b.z * sc, b.w * sc};
      int w0, w1; pack_fp8x8(vv, w0, w1);
      *(int2*)(wbt8 + (size_t)(o0 + o_l) * K2 + j0 + i_l * 8) = make_int2(w0, w1);
    }
  } else {
    // ---- per-row x prep: silu (bf16) + RBF bases (fp8) ----
    const int b = bx - 512;
    const float inv_sigma = 1.0f / sigma[0];
    const float* xrow = x + (size_t)b * IN_F;
    unsigned char* arow = Ab8 + (size_t)b * K2;
    __bf16* srow = sbA + (size_t)b * IN_F;
    {
      float4 v = ((const float4*)xrow)[t];
      float vv[4] = {v.x, v.y, v.z, v.w};
      union { __bf16 h[4]; uint2 q; } s;
      #pragma unroll
      for (int e = 0; e < 4; ++e) s.h[e] = (__bf16)(vv[e] / (1.0f + __expf(-vv[e])));
      ((uint2*)srow)[t] = s.q;
    }
    #pragma unroll
    for (int it = 0; it < 4; ++it) {
      const int i = t + it * 256;
      const float u = xrow[i];
      float4 g0 = *(const float4*)(grid + (size_t)i * GRID_N);
      float4 g1 = *(const float4*)(grid + (size_t)i * GRID_N + 4);
      float gg[8] = {g0.x, g0.y, g0.z, g0.w, g1.x, g1.y, g1.z, g1.w};
      float bb[8];
      #pragma unroll
      for (int g = 0; g < GRID_N; ++g) {
        float d = (u - gg[g]) * inv_sigma;
        bb[g] = __expf(-d * d);
      }
      int w0, w1; pack_fp8x8(bb, w0, w1);
      *(int2*)(arow + (size_t)i * GRID_N) = make_int2(w0, w1);
    }
  }
}

// ---------- launch 2: unified GEMM, 256x128 tile, 8 waves, 2ph prefetch ----------
// fp8 MX phase (K=8192 bytes, 64 steps) then bf16 phase (K=1024, 16 steps),
// shared accumulator. Double-buffered LDS: 2 x (A 32KB + B 16KB) = 96KB.
__global__ __launch_bounds__(512, 2)
void kan_gemm_all(const unsigned char* __restrict__ Ab8,
                  const unsigned char* __restrict__ wbt8,
                  const __bf16* __restrict__ sbA,
                  const __bf16* __restrict__ sbT,
                  float* __restrict__ out) {
  __shared__ unsigned char smem[2][49152];   // [buf][A:0..32K | B:32K..48K]

  const int tid = threadIdx.x;
  const int bx  = blockIdx.x;
  // XCD swizzle (256 blocks, 8 XCDs): xcd owns 4 row-panels x 8 col-panels,
  // so the per-K-step A/B chunks of its working set stay L2-resident.
  const int xcd = bx & 7, loc = bx >> 3;
  const int r0 = (xcd * 4 + (loc >> 3)) * 256;
  const int c0 = (loc & 7) * 128;

  const int lane = tid & 63, wave = tid >> 6;
  const int wm = wave & 3, wn = wave >> 2;     // 4(M) x 2(N) waves, 64x64 each
  const int quad = lane >> 4, l15 = lane & 15;

  // ---- LDS read offsets (byte), XOR-swizzled ----
  int a_off8[4][2], b_off8[4][2];
  #pragma unroll
  for (int t4 = 0; t4 < 4; ++t4) {
    const int rowA = wm * 64 + t4 * 16 + l15;   // [0,256)
    const int rowB = wn * 64 + t4 * 16 + l15;   // [0,128)
    #pragma unroll
    for (int h = 0; h < 2; ++h) {
      a_off8[t4][h] = rowA * 128 + (((quad * 2 + h) ^ (rowA & 7)) * 16);
      b_off8[t4][h] = 32768 + rowB * 128 + (((quad * 2 + h) ^ (rowB & 7)) * 16);
    }
  }
  int a_off16[2][4], b_off16[2][4];
  #pragma unroll
  for (int ks = 0; ks < 2; ++ks) {
    const int kc = ks * 4 + quad;
    #pragma unroll
    for (int t4 = 0; t4 < 4; ++t4) {
      const int rowA = wm * 64 + t4 * 16 + l15;
      a_off16[ks][t4] = (rowA * 8 + (kc ^ (rowA & 7))) * 16;
      const int rowB = wn * 64 + t4 * 16 + l15;
      b_off16[ks][t4] = 32768 + (rowB * 8 + (kc ^ (rowB & 7))) * 16;
    }
  }

  // ---- staging sources (global pre-swizzled) + linear LDS dests ----
  // A tile: 256 rows x 128B = 2048 x 16B chunks -> 4 rounds of 512 threads.
  // B tile: 128 rows x 128B = 1024 chunks      -> 2 rounds.
  const unsigned char* aS8[4]; const __bf16* aS16[4]; int aD[4];
  #pragma unroll
  for (int it = 0; it < 4; ++it) {
    const int p = it * 512 + tid;
    const int row = p >> 3;
    const int kc  = (p & 7) ^ (row & 7);
    aS8[it]  = Ab8 + (size_t)(r0 + row) * K2 + kc * 16;
    aS16[it] = sbA + (size_t)(r0 + row) * IN_F + kc * 8;
    aD[it] = p * 16;
  }
  const unsigned char* bS8[2]; const __bf16* bS16[2]; int bD[2];
  #pragma unroll
  for (int it = 0; it < 2; ++it) {
    const int q = it * 512 + tid;
    const int row = q >> 3;
    const int kc  = (q & 7) ^ (row & 7);
    bS8[it]  = wbt8 + (size_t)(c0 + row) * K2 + kc * 16;
    bS16[it] = sbT + (size_t)(c0 + row) * IN_F + kc * 8;
    bD[it] = 32768 + q * 16;
  }

  f32x4 zero; zero[0] = 0.f; zero[1] = 0.f; zero[2] = 0.f; zero[3] = 0.f;
  f32x4 acc[4][4];
  #pragma unroll
  for (int a = 0; a < 4; ++a)
    #pragma unroll
    for (int b = 0; b < 4; ++b) acc[a][b] = zero;

  // ---- prologue: stage fp8 tile 0 into buf 0 ----
  #pragma unroll
  for (int it = 0; it < 4; ++it) gl2lds16(aS8[it], &smem[0][aD[it]]);
  #pragma unroll
  for (int it = 0; it < 2; ++it) gl2lds16(bS8[it], &smem[0][bD[it]]);
  __syncthreads();   // implicit vmcnt(0) drain

  int cur = 0;
  // ---- phase 1: fp8 MX spline, 64 K-steps, prefetch-overlapped ----
  for (int t = 0; t < 64; ++t) {
    const int nxt = cur ^ 1;
    if (t < 63) {                       // stage next fp8 tile
      const int kb = (t + 1) * BK8;
      #pragma unroll
      for (int it = 0; it < 4; ++it) gl2lds16(aS8[it] + kb, &smem[nxt][aD[it]]);
      #pragma unroll
      for (int it = 0; it < 2; ++it) gl2lds16(bS8[it] + kb, &smem[nxt][bD[it]]);
    } else {                            // chain: stage first bf16 tile
      #pragma unroll
      for (int it = 0; it < 4; ++it) gl2lds16(aS16[it], &smem[nxt][aD[it]]);
      #pragma unroll
      for (int it = 0; it < 2; ++it) gl2lds16(bS16[it], &smem[nxt][bD[it]]);
    }
    const unsigned char* sp = smem[cur];
    union frag { int32x8 v; uint4 q[2]; };
    frag af[4], bfv[4];
    #pragma unroll
    for (int t4 = 0; t4 < 4; ++t4) {
      af[t4].q[0]  = *(const uint4*)(sp + a_off8[t4][0]);
      af[t4].q[1]  = *(const uint4*)(sp + a_off8[t4][1]);
      bfv[t4].q[0] = *(const uint4*)(sp + b_off8[t4][0]);
      bfv[t4].q[1] = *(const uint4*)(sp + b_off8[t4][1]);
    }
    __builtin_amdgcn_s_setprio(1);
    #pragma unroll
    for (int tm = 0; tm < 4; ++tm)
      #pragma unroll
      for (int tn = 0; tn < 4; ++tn)
        acc[tm][tn] = __builtin_amdgcn_mfma_scale_f32_16x16x128_f8f6f4(
            af[tm].v, bfv[tn].v, acc[tm][tn],
            0, 0, 0, 0x7F7F7F7F, 0, 0x7F7F7F7F);
    __builtin_amdgcn_s_setprio(0);
    __syncthreads();   // drains this iter's staging; all reads of cur done
    cur = nxt;
  }

  // ---- phase 2: bf16 base, 16 K-steps, same structure, same acc ----
  for (int t = 0; t < 16; ++t) {
    const int nxt = cur ^ 1;
    if (t < 15) {
      const int ke = (t + 1) * BK;      // element offset
      #pragma unroll
      for (int it = 0; it < 4; ++it) gl2lds16(aS16[it] + ke, &smem[nxt][aD[it]]);
      #pragma unroll
      for (int it = 0; it < 2; ++it) gl2lds16(bS16[it] + ke, &smem[nxt][bD[it]]);
    }
    const unsigned char* sp = smem[cur];
    #pragma unroll
    for (int ks = 0; ks < 2; ++ks) {
      bf16x8 af[4], bfv[4];
      #pragma unroll
      for (int t4 = 0; t4 < 4; ++t4) af[t4]  = *(const bf16x8*)(sp + a_off16[ks][t4]);
      #pragma unroll
      for (int t4 = 0; t4 < 4; ++t4) bfv[t4] = *(const bf16x8*)(sp + b_off16[ks][t4]);
      __builtin_amdgcn_s_setprio(1);
      #pragma unroll
      for (int tm = 0; tm < 4; ++tm)
        #pragma unroll
        for (int tn = 0; tn < 4; ++tn)
          acc[tm][tn] = __builtin_amdgcn_mfma_f32_16x16x32_bf16(
              af[tm], bfv[tn], acc[tm][tn], 0, 0, 0);
      __builtin_amdgcn_s_setprio(0);
    }
    __syncthreads();
    cur = nxt;
  }

  // ---- epilogue: plain store ----
  #pragma unroll
  for (int tm = 0; tm < 4; ++tm) {
    const int row = r0 + wm * 64 + tm * 16 + quad * 4;
    #pragma unroll
    for (int tn = 0; tn < 4; ++tn) {
      const int col = c0 + wn * 64 + tn * 16 + l15;
      float* op = out + (size_t)row * OUT_F + col;
      #pragma unroll
      for (int r = 0; r < 4; ++r)
        op[(size_t)r * OUT_F] = acc[tm][tn][r];
    }
  }
}

// ---------- fallback path (ws too small): full-W bf16 prep + fused gemm ----------
__global__ __launch_bounds__(256)
void kan_prep_w_full(const float* __restrict__ sb, const float* __restrict__ sw,
                     const float* __restrict__ ss, __bf16* __restrict__ wbt) {
  const int t = threadIdx.x;
  if (blockIdx.x < 256) {
    __shared__ float tile[64][65];
    const int o0 = (blockIdx.x & 15) * 64, k0 = (blockIdx.x >> 4) * 64;
    const int r = t >> 4, c4 = (t & 15) * 4;
    #pragma unroll
    for (int it = 0; it < 4; ++it) {
      const int k = k0 + r + it * 16;
      float4 v = *(const float4*)(sb + (size_t)k * OUT_F + o0 + c4);
      tile[r + it * 16][c4 + 0] = v.x; tile[r + it * 16][c4 + 1] = v.y;
      tile[r + it * 16][c4 + 2] = v.z; tile[r + it * 16][c4 + 3] = v.w;
    }
    __syncthreads();
    #pragma unroll
    for (int it = 0; it < 4; ++it) {
      const int ol = r + it * 16;
      union { __bf16 h[4]; uint2 q; } s;
      #pragma unroll
      for (int e = 0; e < 4; ++e) s.h[e] = (__bf16)tile[c4 + e][ol];
      *(uint2*)(wbt + (size_t)(o0 + ol) * KTOT + k0 + c4) = s.q;
    }
  } else {
    const size_t e = ((size_t)(blockIdx.x - 256) * 256 + t) * 8;
    const int o = (int)(e >> 13);
    const int j = (int)(e & 8191);
    const int i = j >> 3;
    const float sc = ss[(size_t)i * OUT_F + o];
    float4 a = *(const float4*)(sw + e);
    float4 b = *(const float4*)(sw + e + 4);
    float vv[8] = {a.x, a.y, a.z, a.w, b.x, b.y, b.z, b.w};
    union { __bf16 h[8]; uint4 q; } s;
    #pragma unroll
    for (int g = 0; g < 8; ++g) s.h[g] = (__bf16)(vv[g] * sc);
    *(uint4*)(wbt + (size_t)o * KTOT + IN_F + j) = s.q;
  }
}

__global__ __launch_bounds__(256, 2)
void kan_gemm_fused(const float* __restrict__ x, const __bf16* __restrict__ wbt,
                    const float* __restrict__ grid, const float* __restrict__ sigma,
                    float* __restrict__ out) {
  __shared__ __bf16 As[BM * BK];
  __shared__ __bf16 Bs[BN * BK];
  __shared__ float  gLds[IN_F * GRID_N];
  const int tid = threadIdx.x;
  const int bx  = blockIdx.x;
  const int c0  = (bx & 7) * BN;
  const int r0  = (bx >> 3) * BM;
  for (int idx = tid; idx < IN_F * GRID_N / 4; idx += 256)
    ((float4*)gLds)[idx] = ((const float4*)grid)[idx];
  const float inv_sigma = 1.0f / sigma[0];
  const int lane = tid & 63, wave = tid >> 6;
  const int wm = wave & 1, wn = wave >> 1;
  const int quad = lane >> 4, l15 = lane & 15;
  f32x4 zero; zero[0] = 0.f; zero[1] = 0.f; zero[2] = 0.f; zero[3] = 0.f;
  f32x4 acc[4][4];
  #pragma unroll
  for (int a = 0; a < 4; ++a)
    #pragma unroll
    for (int b = 0; b < 4; ++b) acc[a][b] = zero;
  const int m = tid >> 1, half = tid & 1;
  const float* xrow = x + (size_t)(r0 + m) * IN_F;
  __syncthreads();
  for (int kb = 0; kb < KTOT; kb += BK) {
    union { __bf16 h[32]; uint4 q[4]; } av;
    if (kb < IN_F) {
      const float4* xp = (const float4*)(xrow + kb + half * 32);
      #pragma unroll
      for (int j4 = 0; j4 < 8; ++j4) {
        float4 v = xp[j4];
        float vv[4] = {v.x, v.y, v.z, v.w};
        #pragma unroll
        for (int e = 0; e < 4; ++e)
          av.h[j4 * 4 + e] = (__bf16)(vv[e] / (1.0f + __expf(-vv[e])));
      }
    } else {
      const int i0 = (kb - IN_F) >> 3;
      float4 xv = *(const float4*)(xrow + i0 + half * 4);
      float xs[4] = {xv.x, xv.y, xv.z, xv.w};
      #pragma unroll
      for (int ii = 0; ii < 4; ++ii) {
        const float u = xs[ii];
        const float* gp = &gLds[(i0 + half * 4 + ii) * GRID_N];
        #pragma unroll
        for (int g = 0; g < GRID_N; ++g) {
          float d = (u - gp[g]) * inv_sigma;
          av.h[ii * 8 + g] = (__bf16)__expf(-d * d);
        }
      }
    }
    __syncthreads();
    {
      uint4* dst = (uint4*)&As[m * BK + half * 32];
      #pragma unroll
      for (int qd = 0; qd < 4; ++qd) dst[qd] = av.q[qd];
    }
    #pragma unroll
    for (int it = 0; it < 4; ++it) {
      const int idx = it * 2048 + tid * 8;
      const int n = idx >> 6, k = idx & 63;
      gl2lds16(wbt + (size_t)(c0 + n) * KTOT + kb + k, &Bs[idx]);
    }
    __syncthreads();
    #pragma unroll
    for (int ks = 0; ks < 2; ++ks) {
      bf16x8 af[4], bfv[4];
      #pragma unroll
      for (int t4 = 0; t4 < 4; ++t4)
        af[t4] = *(const bf16x8*)&As[(wm * 64 + t4 * 16 + l15) * BK + ks * 32 + quad * 8];
      #pragma unroll
      for (int t4 = 0; t4 < 4; ++t4)
        bfv[t4] = *(const bf16x8*)&Bs[(wn * 64 + t4 * 16 + l15) * BK + ks * 32 + quad * 8];
      #pragma unroll
      for (int tm = 0; tm < 4; ++tm)
        #pragma unroll
        for (int tn = 0; tn < 4; ++tn)
          acc[tm][tn] = __builtin_amdgcn_mfma_f32_16x16x32_bf16(
              af[tm], bfv[tn], acc[tm][tn], 0, 0, 0);
    }
  }
  #pragma unroll
  for (int tm = 0; tm < 4; ++tm) {
    const int row = r0 + wm * 64 + tm * 16 + quad * 4;
    #pragma unroll
    for (int tn = 0; tn < 4; ++tn) {
      const int col = c0 + wn * 64 + tn * 16 + l15;
      float* op = out + (size_t)row * OUT_F + col;
      #pragma unroll
      for (int r = 0; r < 4; ++r)
        op[(size_t)r * OUT_F] = acc[tm][tn][r];
    }
  }
}

extern "C" void kernel_launch(void* const* d_in, const int* in_sizes, int n_in,
                              void* d_out, int out_size, void* d_ws, size_t ws_size,
                              hipStream_t stream) {
  const float* x     = (const float*)d_in[0];
  const float* sb    = (const float*)d_in[1];
  const float* sw    = (const float*)d_in[2];
  const float* ss    = (const float*)d_in[3];
  const float* grid  = (const float*)d_in[4];
  const float* sigma = (const float*)d_in[5];
  float* out = (float*)d_out;

  const size_t SBT_BYTES = (size_t)OUT_F * IN_F * 2;   //   2 MB (bf16)
  const size_t WS_BYTES  = (size_t)OUT_F * K2;         //  8.4 MB (fp8)
  const size_t A_BYTES   = (size_t)BATCH * K2;         // 67.1 MB (fp8)
  const size_t SBA_BYTES = (size_t)BATCH * IN_F * 2;   // 16.8 MB (bf16)

  if (ws_size >= SBT_BYTES + WS_BYTES + A_BYTES + SBA_BYTES) {
    __bf16*        sbT  = (__bf16*)d_ws;
    unsigned char* wbt8 = (unsigned char*)d_ws + SBT_BYTES;
    unsigned char* Ab8  = (unsigned char*)d_ws + SBT_BYTES + WS_BYTES;
    __bf16*        sbA  = (__bf16*)((char*)d_ws + SBT_BYTES + WS_BYTES + A_BYTES);
    kan_mix<<<dim3(512 + BATCH), dim3(256), 0, stream>>>(
        x, sb, sw, ss, grid, sigma, sbT, wbt8, Ab8, sbA);
    kan_gemm_all<<<dim3((BATCH / 256) * (OUT_F / 128)), dim3(512), 0, stream>>>(
        Ab8, wbt8, sbA, sbT, out);
  } else {
    __bf16* wbt = (__bf16*)d_ws;   // 18.9 MB
    kan_prep_w_full<<<dim3(4352), dim3(256), 0, stream>>>(sb, sw, ss, wbt);
    kan_gemm_fused<<<dim3((BATCH / BM) * (OUT_F / BN)), dim3(256), 0, stream>>>(
        x, wbt, grid, sigma, out);
  }
}

// Round 2
// 231.136 us; speedup vs baseline: 1.0572x; 1.0572x over previous
//
#include <hip/hip_runtime.h>

// KanLinear: out[b,o] = silu(x)@scale_base + bases@(spline_w*scale_spline)
// Round 11:
//  - REVERT gemm to the proven round-9 structure (128x128, 256 thr, 2 blk/CU,
//    2-barrier loop = 104us known-good). Round-10's 256x128/8-wave/96KB-dbuf
//    regressed (115us): 1 blk/CU + vmcnt(0) drain killed memory-level
//    parallelism (12.3 -> 8.3 TB/s sustained tile traffic).
//  - ONLY change vs round-9: XCD swizzle now maps col-panel == XCD
//    (c0 = (bx&7)*BN, r0 = (bx>>3)*BM). Each XCD's B slice (1MB fp8) and
//    sbT slice (256KB) stay L2-resident; all 64 blocks of an XCD touch the
//    same 16KB B-chunk per K-step in lockstep -> 1 L3 fill + 63 L2 hits.
//    L3-level tile traffic 1.28GB -> ~650MB. Predict gemm 104 -> 55-70us,
//    MfmaUtil ~2x.
//  - kan_mix untouched.

#define BATCH 8192
#define IN_F  1024
#define OUT_F 1024
#define GRID_N 8
#define K2    (IN_F * GRID_N)          // spline K = 8192
#define KTOT  (IN_F + K2)              // 9216 (fallback path)

#define BM 128
#define BN 128
#define BK 64        // bf16 k-tile
#define BK8 128      // fp8 k-tile (bytes)

typedef __bf16 bf16x8 __attribute__((ext_vector_type(8)));
typedef float  f32x4  __attribute__((ext_vector_type(4)));
typedef int    int32x8 __attribute__((ext_vector_type(8)));

__device__ __forceinline__ void gl2lds16(const void* g, void* l) {
  __builtin_amdgcn_global_load_lds(
      (const __attribute__((address_space(1))) void*)g,
      (__attribute__((address_space(3))) void*)l, 16, 0, 0);
}

__device__ __forceinline__ void pack_fp8x8(const float* v, int& w0, int& w1) {
  w0 = 0; w1 = 0;
  w0 = __builtin_amdgcn_cvt_pk_fp8_f32(v[0], v[1], w0, false);
  w0 = __builtin_amdgcn_cvt_pk_fp8_f32(v[2], v[3], w0, true);
  w1 = __builtin_amdgcn_cvt_pk_fp8_f32(v[4], v[5], w1, false);
  w1 = __builtin_amdgcn_cvt_pk_fp8_f32(v[6], v[7], w1, true);
}

// ---------- launch 1: pure elementwise prep, all streams coalesced ----------
// blocks [0,256):      sbT[o][k] = (bf16)scale_base[k][o]  (LDS transpose)
// blocks [256,512):    spline-pack tile 64o x 512j with LDS-staged ss
// blocks [512,8704):   row b: sbA[b][k]=bf16(silu(x)), Ab8[b][i*8+g]=fp8(base)
__global__ __launch_bounds__(256)
void kan_mix(const float* __restrict__ x, const float* __restrict__ sb,
             const float* __restrict__ sw, const float* __restrict__ ss,
             const float* __restrict__ grid, const float* __restrict__ sigma,
             __bf16* __restrict__ sbT, unsigned char* __restrict__ wbt8,
             unsigned char* __restrict__ Ab8, __bf16* __restrict__ sbA) {
  const int t = threadIdx.x;
  const int bx = blockIdx.x;
  if (bx < 256) {
    // ---- sb transpose (64x64 f32 tiles) ----
    __shared__ float tile[64][65];
    const int o0 = (bx & 15) * 64, k0 = (bx >> 4) * 64;
    const int r = t >> 4, c4 = (t & 15) * 4;
    #pragma unroll
    for (int it = 0; it < 4; ++it) {
      const int k = k0 + r + it * 16;
      float4 v = *(const float4*)(sb + (size_t)k * OUT_F + o0 + c4);
      tile[r + it * 16][c4 + 0] = v.x; tile[r + it * 16][c4 + 1] = v.y;
      tile[r + it * 16][c4 + 2] = v.z; tile[r + it * 16][c4 + 3] = v.w;
    }
    __syncthreads();
    #pragma unroll
    for (int it = 0; it < 4; ++it) {
      const int ol = r + it * 16;
      union { __bf16 h[4]; uint2 q; } s;
      #pragma unroll
      for (int e = 0; e < 4; ++e) s.h[e] = (__bf16)tile[c4 + e][ol];
      *(uint2*)(sbT + (size_t)(o0 + ol) * IN_F + k0 + c4) = s.q;
    }
  } else if (bx < 512) {
    // ---- spline-pack: tile = o in [o0,o0+64), j in [j0,j0+512), i=j/8 ----
    __shared__ float tile[64][65];        // tile[i_local][o_local]
    const int sp = bx - 256;              // [0,256)
    const int o0 = (sp >> 4) * 64;
    const int j0 = (sp & 15) * 512;
    const int i0 = j0 >> 3;               // 64 i's per tile
    // stage ss[i0..i0+64)[o0..o0+64) coalesced (float4 per lane)
    const int r = t >> 4, c4 = (t & 15) * 4;
    #pragma unroll
    for (int it = 0; it < 4; ++it) {
      const int i = i0 + r + it * 16;
      float4 v = *(const float4*)(ss + (size_t)i * OUT_F + o0 + c4);
      tile[r + it * 16][c4 + 0] = v.x; tile[r + it * 16][c4 + 1] = v.y;
      tile[r + it * 16][c4 + 2] = v.z; tile[r + it * 16][c4 + 3] = v.w;
    }
    __syncthreads();
    // pack: pass p handles flat f = p*256+t over 4096 (o_l,i_l) pairs,
    // i_l fastest -> sw reads & wbt8 writes fully coalesced.
    #pragma unroll
    for (int p = 0; p < 16; ++p) {
      const int f = p * 256 + t;
      const int o_l = f >> 6, i_l = f & 63;
      const float sc = tile[i_l][o_l];
      const float* swp = sw + (size_t)(o0 + o_l) * K2 + j0 + i_l * 8;
      float4 a = *(const float4*)swp;
      float4 b = *(const float4*)(swp + 4);
      float vv[8] = {a.x * sc, a.y * sc, a.z * sc, a.w * sc,
                     b.x * sc, b.y * sc, b.z * sc, b.w * sc};
      int w0, w1; pack_fp8x8(vv, w0, w1);
      *(int2*)(wbt8 + (size_t)(o0 + o_l) * K2 + j0 + i_l * 8) = make_int2(w0, w1);
    }
  } else {
    // ---- per-row x prep: silu (bf16) + RBF bases (fp8) ----
    const int b = bx - 512;
    const float inv_sigma = 1.0f / sigma[0];
    const float* xrow = x + (size_t)b * IN_F;
    unsigned char* arow = Ab8 + (size_t)b * K2;
    __bf16* srow = sbA + (size_t)b * IN_F;
    {
      float4 v = ((const float4*)xrow)[t];
      float vv[4] = {v.x, v.y, v.z, v.w};
      union { __bf16 h[4]; uint2 q; } s;
      #pragma unroll
      for (int e = 0; e < 4; ++e) s.h[e] = (__bf16)(vv[e] / (1.0f + __expf(-vv[e])));
      ((uint2*)srow)[t] = s.q;
    }
    #pragma unroll
    for (int it = 0; it < 4; ++it) {
      const int i = t + it * 256;
      const float u = xrow[i];
      float4 g0 = *(const float4*)(grid + (size_t)i * GRID_N);
      float4 g1 = *(const float4*)(grid + (size_t)i * GRID_N + 4);
      float gg[8] = {g0.x, g0.y, g0.z, g0.w, g1.x, g1.y, g1.z, g1.w};
      float bb[8];
      #pragma unroll
      for (int g = 0; g < GRID_N; ++g) {
        float d = (u - gg[g]) * inv_sigma;
        bb[g] = __expf(-d * d);
      }
      int w0, w1; pack_fp8x8(bb, w0, w1);
      *(int2*)(arow + (size_t)i * GRID_N) = make_int2(w0, w1);
    }
  }
}

// ---------- launch 2: unified GEMM, fp8 phase (K=8192) + bf16 phase (K=1024) ----------
// Round-9 structure (proven 104us). Swizzle change only: col-panel == XCD.
__global__ __launch_bounds__(256)
void kan_gemm_all(const unsigned char* __restrict__ Ab8,
                  const unsigned char* __restrict__ wbt8,
                  const __bf16* __restrict__ sbA,
                  const __bf16* __restrict__ sbT,
                  float* __restrict__ out) {
  __shared__ unsigned char As8[BM * BK8];   // 16 KB; bf16 phase aliases it
  __shared__ unsigned char Bs8[BN * BK8];   // 16 KB
  __bf16* As16 = (__bf16*)As8;
  __bf16* Bs16 = (__bf16*)Bs8;

  const int tid = threadIdx.x;
  const int bx  = blockIdx.x;
  // col-panel == XCD: each XCD's B slice (1MB) / sbT slice (256KB) stays
  // L2-resident; its 64 blocks touch the same 16KB B-chunk per K-step.
  // Row-panels advance bx>>3: 8 consecutive blocks = same A row-panel on
  // 8 different XCDs -> one HBM/L3 fill serves all 8.
  const int r0  = (bx >> 3) * BM;
  const int c0  = (bx & 7) * BN;

  const int lane = tid & 63, wave = tid >> 6;
  const int wm = wave & 1, wn = wave >> 1;
  const int quad = lane >> 4, l15 = lane & 15;

  int a_off8[4][2], b_off8[4][2];
  #pragma unroll
  for (int t4 = 0; t4 < 4; ++t4) {
    const int rowA = wm * 64 + t4 * 16 + l15;
    const int rowB = wn * 64 + t4 * 16 + l15;
    #pragma unroll
    for (int h = 0; h < 2; ++h) {
      a_off8[t4][h] = rowA * BK8 + (((quad * 2 + h) ^ (rowA & 7)) * 16);
      b_off8[t4][h] = rowB * BK8 + (((quad * 2 + h) ^ (rowB & 7)) * 16);
    }
  }
  int a_off16[2][4], b_off16[2][4];
  #pragma unroll
  for (int ks = 0; ks < 2; ++ks) {
    const int kc = ks * 4 + quad;
    #pragma unroll
    for (int t4 = 0; t4 < 4; ++t4) {
      const int rowA = wm * 64 + t4 * 16 + l15;
      a_off16[ks][t4] = (rowA * 8 + (kc ^ (rowA & 7))) * 8;
      const int rowB = wn * 64 + t4 * 16 + l15;
      b_off16[ks][t4] = (rowB * 8 + (kc ^ (rowB & 7))) * 8;
    }
  }
  const unsigned char* aSrc8[4]; const unsigned char* bSrc8[4];
  const __bf16* aSrc16[4]; const __bf16* bSrc16[4]; int dstOff[4];
  #pragma unroll
  for (int it = 0; it < 4; ++it) {
    const int p = it * 256 + tid;
    const int row = p >> 3;
    const int kc  = (p & 7) ^ (row & 7);
    aSrc8[it]  = Ab8  + (size_t)(r0 + row) * K2 + kc * 16;
    bSrc8[it]  = wbt8 + (size_t)(c0 + row) * K2 + kc * 16;
    aSrc16[it] = sbA  + (size_t)(r0 + row) * IN_F + kc * 8;
    bSrc16[it] = sbT  + (size_t)(c0 + row) * IN_F + kc * 8;
    dstOff[it] = p * 16;
  }

  f32x4 zero; zero[0] = 0.f; zero[1] = 0.f; zero[2] = 0.f; zero[3] = 0.f;
  f32x4 acc[4][4];
  #pragma unroll
  for (int a = 0; a < 4; ++a)
    #pragma unroll
    for (int b = 0; b < 4; ++b) acc[a][b] = zero;

  // ---- phase 1: fp8 MX spline, 64 iters ----
  for (int kb = 0; kb < K2; kb += BK8) {
    __syncthreads();
    #pragma unroll
    for (int it = 0; it < 4; ++it) {
      gl2lds16(aSrc8[it] + kb, &As8[dstOff[it]]);
      gl2lds16(bSrc8[it] + kb, &Bs8[dstOff[it]]);
    }
    __syncthreads();
    union frag { int32x8 v; uint4 q[2]; };
    frag af[4], bfv[4];
    #pragma unroll
    for (int t4 = 0; t4 < 4; ++t4) {
      af[t4].q[0]  = *(const uint4*)&As8[a_off8[t4][0]];
      af[t4].q[1]  = *(const uint4*)&As8[a_off8[t4][1]];
      bfv[t4].q[0] = *(const uint4*)&Bs8[b_off8[t4][0]];
      bfv[t4].q[1] = *(const uint4*)&Bs8[b_off8[t4][1]];
    }
    #pragma unroll
    for (int tm = 0; tm < 4; ++tm)
      #pragma unroll
      for (int tn = 0; tn < 4; ++tn)
        acc[tm][tn] = __builtin_amdgcn_mfma_scale_f32_16x16x128_f8f6f4(
            af[tm].v, bfv[tn].v, acc[tm][tn],
            0, 0, 0, 0x7F7F7F7F, 0, 0x7F7F7F7F);
  }

  // ---- phase 2: bf16 base, 16 iters (same acc) ----
  for (int kb = 0; kb < IN_F; kb += BK) {
    __syncthreads();
    #pragma unroll
    for (int it = 0; it < 4; ++it) {
      gl2lds16(aSrc16[it] + kb, (char*)As16 + dstOff[it]);
      gl2lds16(bSrc16[it] + kb, (char*)Bs16 + dstOff[it]);
    }
    __syncthreads();
    #pragma unroll
    for (int ks = 0; ks < 2; ++ks) {
      bf16x8 af[4], bfv[4];
      #pragma unroll
      for (int t4 = 0; t4 < 4; ++t4) af[t4]  = *(const bf16x8*)&As16[a_off16[ks][t4]];
      #pragma unroll
      for (int t4 = 0; t4 < 4; ++t4) bfv[t4] = *(const bf16x8*)&Bs16[b_off16[ks][t4]];
      #pragma unroll
      for (int tm = 0; tm < 4; ++tm)
        #pragma unroll
        for (int tn = 0; tn < 4; ++tn)
          acc[tm][tn] = __builtin_amdgcn_mfma_f32_16x16x32_bf16(
              af[tm], bfv[tn], acc[tm][tn], 0, 0, 0);
    }
  }

  // ---- epilogue: plain store ----
  #pragma unroll
  for (int tm = 0; tm < 4; ++tm) {
    const int row = r0 + wm * 64 + tm * 16 + quad * 4;
    #pragma unroll
    for (int tn = 0; tn < 4; ++tn) {
      const int col = c0 + wn * 64 + tn * 16 + l15;
      float* op = out + (size_t)row * OUT_F + col;
      #pragma unroll
      for (int r = 0; r < 4; ++r)
        op[(size_t)r * OUT_F] = acc[tm][tn][r];
    }
  }
}

// ---------- fallback path (ws too small): full-W bf16 prep + fused gemm ----------
__global__ __launch_bounds__(256)
void kan_prep_w_full(const float* __restrict__ sb, const float* __restrict__ sw,
                     const float* __restrict__ ss, __bf16* __restrict__ wbt) {
  const int t = threadIdx.x;
  if (blockIdx.x < 256) {
    __shared__ float tile[64][65];
    const int o0 = (blockIdx.x & 15) * 64, k0 = (blockIdx.x >> 4) * 64;
    const int r = t >> 4, c4 = (t & 15) * 4;
    #pragma unroll
    for (int it = 0; it < 4; ++it) {
      const int k = k0 + r + it * 16;
      float4 v = *(const float4*)(sb + (size_t)k * OUT_F + o0 + c4);
      tile[r + it * 16][c4 + 0] = v.x; tile[r + it * 16][c4 + 1] = v.y;
      tile[r + it * 16][c4 + 2] = v.z; tile[r + it * 16][c4 + 3] = v.w;
    }
    __syncthreads();
    #pragma unroll
    for (int it = 0; it < 4; ++it) {
      const int ol = r + it * 16;
      union { __bf16 h[4]; uint2 q; } s;
      #pragma unroll
      for (int e = 0; e < 4; ++e) s.h[e] = (__bf16)tile[c4 + e][ol];
      *(uint2*)(wbt + (size_t)(o0 + ol) * KTOT + k0 + c4) = s.q;
    }
  } else {
    const size_t e = ((size_t)(blockIdx.x - 256) * 256 + t) * 8;
    const int o = (int)(e >> 13);
    const int j = (int)(e & 8191);
    const int i = j >> 3;
    const float sc = ss[(size_t)i * OUT_F + o];
    float4 a = *(const float4*)(sw + e);
    float4 b = *(const float4*)(sw + e + 4);
    float vv[8] = {a.x, a.y, a.z, a.w, b.x, b.y, b.z, b.w};
    union { __bf16 h[8]; uint4 q; } s;
    #pragma unroll
    for (int g = 0; g < 8; ++g) s.h[g] = (__bf16)(vv[g] * sc);
    *(uint4*)(wbt + (size_t)o * KTOT + IN_F + j) = s.q;
  }
}

__global__ __launch_bounds__(256, 2)
void kan_gemm_fused(const float* __restrict__ x, const __bf16* __restrict__ wbt,
                    const float* __restrict__ grid, const float* __restrict__ sigma,
                    float* __restrict__ out) {
  __shared__ __bf16 As[BM * BK];
  __shared__ __bf16 Bs[BN * BK];
  __shared__ float  gLds[IN_F * GRID_N];
  const int tid = threadIdx.x;
  const int bx  = blockIdx.x;
  const int c0  = (bx & 7) * BN;
  const int r0  = (bx >> 3) * BM;
  for (int idx = tid; idx < IN_F * GRID_N / 4; idx += 256)
    ((float4*)gLds)[idx] = ((const float4*)grid)[idx];
  const float inv_sigma = 1.0f / sigma[0];
  const int lane = tid & 63, wave = tid >> 6;
  const int wm = wave & 1, wn = wave >> 1;
  const int quad = lane >> 4, l15 = lane & 15;
  f32x4 zero; zero[0] = 0.f; zero[1] = 0.f; zero[2] = 0.f; zero[3] = 0.f;
  f32x4 acc[4][4];
  #pragma unroll
  for (int a = 0; a < 4; ++a)
    #pragma unroll
    for (int b = 0; b < 4; ++b) acc[a][b] = zero;
  const int m = tid >> 1, half = tid & 1;
  const float* xrow = x + (size_t)(r0 + m) * IN_F;
  __syncthreads();
  for (int kb = 0; kb < KTOT; kb += BK) {
    union { __bf16 h[32]; uint4 q[4]; } av;
    if (kb < IN_F) {
      const float4* xp = (const float4*)(xrow + kb + half * 32);
      #pragma unroll
      for (int j4 = 0; j4 < 8; ++j4) {
        float4 v = xp[j4];
        float vv[4] = {v.x, v.y, v.z, v.w};
        #pragma unroll
        for (int e = 0; e < 4; ++e)
          av.h[j4 * 4 + e] = (__bf16)(vv[e] / (1.0f + __expf(-vv[e])));
      }
    } else {
      const int i0 = (kb - IN_F) >> 3;
      float4 xv = *(const float4*)(xrow + i0 + half * 4);
      float xs[4] = {xv.x, xv.y, xv.z, xv.w};
      #pragma unroll
      for (int ii = 0; ii < 4; ++ii) {
        const float u = xs[ii];
        const float* gp = &gLds[(i0 + half * 4 + ii) * GRID_N];
        #pragma unroll
        for (int g = 0; g < GRID_N; ++g) {
          float d = (u - gp[g]) * inv_sigma;
          av.h[ii * 8 + g] = (__bf16)__expf(-d * d);
        }
      }
    }
    __syncthreads();
    {
      uint4* dst = (uint4*)&As[m * BK + half * 32];
      #pragma unroll
      for (int qd = 0; qd < 4; ++qd) dst[qd] = av.q[qd];
    }
    #pragma unroll
    for (int it = 0; it < 4; ++it) {
      const int idx = it * 2048 + tid * 8;
      const int n = idx >> 6, k = idx & 63;
      gl2lds16(wbt + (size_t)(c0 + n) * KTOT + kb + k, &Bs[idx]);
    }
    __syncthreads();
    #pragma unroll
    for (int ks = 0; ks < 2; ++ks) {
      bf16x8 af[4], bfv[4];
      #pragma unroll
      for (int t4 = 0; t4 < 4; ++t4)
        af[t4] = *(const bf16x8*)&As[(wm * 64 + t4 * 16 + l15) * BK + ks * 32 + quad * 8];
      #pragma unroll
      for (int t4 = 0; t4 < 4; ++t4)
        bfv[t4] = *(const bf16x8*)&Bs[(wn * 64 + t4 * 16 + l15) * BK + ks * 32 + quad * 8];
      #pragma unroll
      for (int tm = 0; tm < 4; ++tm)
        #pragma unroll
        for (int tn = 0; tn < 4; ++tn)
          acc[tm][tn] = __builtin_amdgcn_mfma_f32_16x16x32_bf16(
              af[tm], bfv[tn], acc[tm][tn], 0, 0, 0);
    }
  }
  #pragma unroll
  for (int tm = 0; tm < 4; ++tm) {
    const int row = r0 + wm * 64 + tm * 16 + quad * 4;
    #pragma unroll
    for (int tn = 0; tn < 4; ++tn) {
      const int col = c0 + wn * 64 + tn * 16 + l15;
      float* op = out + (size_t)row * OUT_F + col;
      #pragma unroll
      for (int r = 0; r < 4; ++r)
        op[(size_t)r * OUT_F] = acc[tm][tn][r];
    }
  }
}

extern "C" void kernel_launch(void* const* d_in, const int* in_sizes, int n_in,
                              void* d_out, int out_size, void* d_ws, size_t ws_size,
                              hipStream_t stream) {
  const float* x     = (const float*)d_in[0];
  const float* sb    = (const float*)d_in[1];
  const float* sw    = (const float*)d_in[2];
  const float* ss    = (const float*)d_in[3];
  const float* grid  = (const float*)d_in[4];
  const float* sigma = (const float*)d_in[5];
  float* out = (float*)d_out;

  const size_t SBT_BYTES = (size_t)OUT_F * IN_F * 2;   //   2 MB (bf16)
  const size_t WS_BYTES  = (size_t)OUT_F * K2;         //  8.4 MB (fp8)
  const size_t A_BYTES   = (size_t)BATCH * K2;         // 67.1 MB (fp8)
  const size_t SBA_BYTES = (size_t)BATCH * IN_F * 2;   // 16.8 MB (bf16)

  if (ws_size >= SBT_BYTES + WS_BYTES + A_BYTES + SBA_BYTES) {
    __bf16*        sbT  = (__bf16*)d_ws;
    unsigned char* wbt8 = (unsigned char*)d_ws + SBT_BYTES;
    unsigned char* Ab8  = (unsigned char*)d_ws + SBT_BYTES + WS_BYTES;
    __bf16*        sbA  = (__bf16*)((char*)d_ws + SBT_BYTES + WS_BYTES + A_BYTES);
    kan_mix<<<dim3(512 + BATCH), dim3(256), 0, stream>>>(
        x, sb, sw, ss, grid, sigma, sbT, wbt8, Ab8, sbA);
    kan_gemm_all<<<dim3((BATCH / BM) * (OUT_F / BN)), dim3(256), 0, stream>>>(
        Ab8, wbt8, sbA, sbT, out);
  } else {
    __bf16* wbt = (__bf16*)d_ws;   // 18.9 MB
    kan_prep_w_full<<<dim3(4352), dim3(256), 0, stream>>>(sb, sw, ss, wbt);
    kan_gemm_fused<<<dim3((BATCH / BM) * (OUT_F / BN)), dim3(256), 0, stream>>>(
        x, wbt, grid, sigma, out);
  }
}

// Round 3
// 224.802 us; speedup vs baseline: 1.0869x; 1.0282x over previous
//
#include <hip/hip_runtime.h>

// KanLinear: out[b,o] = silu(x)@scale_base + bases@(spline_w*scale_spline)
// Round 12:
//  - Diagnostic from r11: duration invariant (102us) under 4x HBM traffic
//    change -> gemm is latency/barrier-bound, not traffic-bound. The 2-barrier
//    loop exposes full global-load latency every K-step (vmcnt(0) drain).
//  - Fix: true T3+T4 counted-vmcnt double-buffer on the PROVEN r9 structure:
//    issue prefetch(t+1) -> s_waitcnt vmcnt(8) (prefetch stays in flight!) ->
//    raw s_barrier -> ds_read+MFMA -> raw s_barrier. LDS 2x32KB, still 2
//    blocks/CU. Round-10 failed because __syncthreads() drained vmcnt(0),
//    waiting for the prefetch itself (T4 lesson: counted-vs-drain0 IS the gain).
//  - XCD swizzle reverted to r9 (row-panel group per XCD, FETCH ~82MB
//    compulsory; r11's col-panel==XCD quadrupled HBM traffic for 0 gain).
//  - kan_mix untouched.

#define BATCH 8192
#define IN_F  1024
#define OUT_F 1024
#define GRID_N 8
#define K2    (IN_F * GRID_N)          // spline K = 8192
#define KTOT  (IN_F + K2)              // 9216 (fallback path)

#define BM 128
#define BN 128
#define BK 64        // bf16 k-tile
#define BK8 128      // fp8 k-tile (bytes)

typedef __bf16 bf16x8 __attribute__((ext_vector_type(8)));
typedef float  f32x4  __attribute__((ext_vector_type(4)));
typedef int    int32x8 __attribute__((ext_vector_type(8)));

__device__ __forceinline__ void gl2lds16(const void* g, void* l) {
  __builtin_amdgcn_global_load_lds(
      (const __attribute__((address_space(1))) void*)g,
      (__attribute__((address_space(3))) void*)l, 16, 0, 0);
}

__device__ __forceinline__ void pack_fp8x8(const float* v, int& w0, int& w1) {
  w0 = 0; w1 = 0;
  w0 = __builtin_amdgcn_cvt_pk_fp8_f32(v[0], v[1], w0, false);
  w0 = __builtin_amdgcn_cvt_pk_fp8_f32(v[2], v[3], w0, true);
  w1 = __builtin_amdgcn_cvt_pk_fp8_f32(v[4], v[5], w1, false);
  w1 = __builtin_amdgcn_cvt_pk_fp8_f32(v[6], v[7], w1, true);
}

// ---------- launch 1: pure elementwise prep, all streams coalesced ----------
__global__ __launch_bounds__(256)
void kan_mix(const float* __restrict__ x, const float* __restrict__ sb,
             const float* __restrict__ sw, const float* __restrict__ ss,
             const float* __restrict__ grid, const float* __restrict__ sigma,
             __bf16* __restrict__ sbT, unsigned char* __restrict__ wbt8,
             unsigned char* __restrict__ Ab8, __bf16* __restrict__ sbA) {
  const int t = threadIdx.x;
  const int bx = blockIdx.x;
  if (bx < 256) {
    // ---- sb transpose (64x64 f32 tiles) ----
    __shared__ float tile[64][65];
    const int o0 = (bx & 15) * 64, k0 = (bx >> 4) * 64;
    const int r = t >> 4, c4 = (t & 15) * 4;
    #pragma unroll
    for (int it = 0; it < 4; ++it) {
      const int k = k0 + r + it * 16;
      float4 v = *(const float4*)(sb + (size_t)k * OUT_F + o0 + c4);
      tile[r + it * 16][c4 + 0] = v.x; tile[r + it * 16][c4 + 1] = v.y;
      tile[r + it * 16][c4 + 2] = v.z; tile[r + it * 16][c4 + 3] = v.w;
    }
    __syncthreads();
    #pragma unroll
    for (int it = 0; it < 4; ++it) {
      const int ol = r + it * 16;
      union { __bf16 h[4]; uint2 q; } s;
      #pragma unroll
      for (int e = 0; e < 4; ++e) s.h[e] = (__bf16)tile[c4 + e][ol];
      *(uint2*)(sbT + (size_t)(o0 + ol) * IN_F + k0 + c4) = s.q;
    }
  } else if (bx < 512) {
    // ---- spline-pack: tile = o in [o0,o0+64), j in [j0,j0+512), i=j/8 ----
    __shared__ float tile[64][65];        // tile[i_local][o_local]
    const int sp = bx - 256;              // [0,256)
    const int o0 = (sp >> 4) * 64;
    const int j0 = (sp & 15) * 512;
    const int i0 = j0 >> 3;               // 64 i's per tile
    const int r = t >> 4, c4 = (t & 15) * 4;
    #pragma unroll
    for (int it = 0; it < 4; ++it) {
      const int i = i0 + r + it * 16;
      float4 v = *(const float4*)(ss + (size_t)i * OUT_F + o0 + c4);
      tile[r + it * 16][c4 + 0] = v.x; tile[r + it * 16][c4 + 1] = v.y;
      tile[r + it * 16][c4 + 2] = v.z; tile[r + it * 16][c4 + 3] = v.w;
    }
    __syncthreads();
    #pragma unroll
    for (int p = 0; p < 16; ++p) {
      const int f = p * 256 + t;
      const int o_l = f >> 6, i_l = f & 63;
      const float sc = tile[i_l][o_l];
      const float* swp = sw + (size_t)(o0 + o_l) * K2 + j0 + i_l * 8;
      float4 a = *(const float4*)swp;
      float4 b = *(const float4*)(swp + 4);
      float vv[8] = {a.x * sc, a.y * sc, a.z * sc, a.w * sc,
                     b.x * sc, b.y * sc, b.z * sc, b.w * sc};
      int w0, w1; pack_fp8x8(vv, w0, w1);
      *(int2*)(wbt8 + (size_t)(o0 + o_l) * K2 + j0 + i_l * 8) = make_int2(w0, w1);
    }
  } else {
    // ---- per-row x prep: silu (bf16) + RBF bases (fp8) ----
    const int b = bx - 512;
    const float inv_sigma = 1.0f / sigma[0];
    const float* xrow = x + (size_t)b * IN_F;
    unsigned char* arow = Ab8 + (size_t)b * K2;
    __bf16* srow = sbA + (size_t)b * IN_F;
    {
      float4 v = ((const float4*)xrow)[t];
      float vv[4] = {v.x, v.y, v.z, v.w};
      union { __bf16 h[4]; uint2 q; } s;
      #pragma unroll
      for (int e = 0; e < 4; ++e) s.h[e] = (__bf16)(vv[e] / (1.0f + __expf(-vv[e])));
      ((uint2*)srow)[t] = s.q;
    }
    #pragma unroll
    for (int it = 0; it < 4; ++it) {
      const int i = t + it * 256;
      const float u = xrow[i];
      float4 g0 = *(const float4*)(grid + (size_t)i * GRID_N);
      float4 g1 = *(const float4*)(grid + (size_t)i * GRID_N + 4);
      float gg[8] = {g0.x, g0.y, g0.z, g0.w, g1.x, g1.y, g1.z, g1.w};
      float bb[8];
      #pragma unroll
      for (int g = 0; g < GRID_N; ++g) {
        float d = (u - gg[g]) * inv_sigma;
        bb[g] = __expf(-d * d);
      }
      int w0, w1; pack_fp8x8(bb, w0, w1);
      *(int2*)(arow + (size_t)i * GRID_N) = make_int2(w0, w1);
    }
  }
}

// ---------- launch 2: unified GEMM, counted-vmcnt double-buffered ----------
// fp8 MX phase (K=8192, 64 steps) + bf16 phase (K=1024, 16 steps), shared acc.
__global__ __launch_bounds__(256)
void kan_gemm_all(const unsigned char* __restrict__ Ab8,
                  const unsigned char* __restrict__ wbt8,
                  const __bf16* __restrict__ sbA,
                  const __bf16* __restrict__ sbT,
                  float* __restrict__ out) {
  // [buf][ A: 0..16K | B: 16K..32K ]; 64 KB total -> 2 blocks/CU
  __shared__ unsigned char smem[2][32768];

  const int tid = threadIdx.x;
  const int bx  = blockIdx.x;
  // r9 swizzle: 8 consecutive bx (one per XCD) share a col-panel; each XCD's
  // 64 blocks cover 8 row-panels x 8 col-panels -> A fetched once per XCD.
  const int s   = bx >> 3;
  const int r0  = ((bx & 7) * 8 + (s >> 3)) * BM;
  const int c0  = (s & 7) * BN;

  const int lane = tid & 63, wave = tid >> 6;
  const int wm = wave & 1, wn = wave >> 1;
  const int quad = lane >> 4, l15 = lane & 15;

  // ---- LDS read offsets (bytes), XOR-swizzled; B at +16384 ----
  int a_off8[4][2], b_off8[4][2];
  #pragma unroll
  for (int t4 = 0; t4 < 4; ++t4) {
    const int rowA = wm * 64 + t4 * 16 + l15;
    const int rowB = wn * 64 + t4 * 16 + l15;
    #pragma unroll
    for (int h = 0; h < 2; ++h) {
      a_off8[t4][h] = rowA * BK8 + (((quad * 2 + h) ^ (rowA & 7)) * 16);
      b_off8[t4][h] = 16384 + rowB * BK8 + (((quad * 2 + h) ^ (rowB & 7)) * 16);
    }
  }
  int a_off16[2][4], b_off16[2][4];
  #pragma unroll
  for (int ks = 0; ks < 2; ++ks) {
    const int kc = ks * 4 + quad;
    #pragma unroll
    for (int t4 = 0; t4 < 4; ++t4) {
      const int rowA = wm * 64 + t4 * 16 + l15;
      a_off16[ks][t4] = (rowA * 8 + (kc ^ (rowA & 7))) * 16;
      const int rowB = wn * 64 + t4 * 16 + l15;
      b_off16[ks][t4] = 16384 + (rowB * 8 + (kc ^ (rowB & 7))) * 16;
    }
  }

  // ---- staging sources (global pre-swizzled) + linear LDS dests ----
  const unsigned char* aSrc8[4]; const unsigned char* bSrc8[4];
  const __bf16* aSrc16[4]; const __bf16* bSrc16[4]; int dstOff[4];
  #pragma unroll
  for (int it = 0; it < 4; ++it) {
    const int p = it * 256 + tid;
    const int row = p >> 3;
    const int kc  = (p & 7) ^ (row & 7);
    aSrc8[it]  = Ab8  + (size_t)(r0 + row) * K2 + kc * 16;
    bSrc8[it]  = wbt8 + (size_t)(c0 + row) * K2 + kc * 16;
    aSrc16[it] = sbA  + (size_t)(r0 + row) * IN_F + kc * 8;
    bSrc16[it] = sbT  + (size_t)(c0 + row) * IN_F + kc * 8;
    dstOff[it] = p * 16;
  }

  f32x4 zero; zero[0] = 0.f; zero[1] = 0.f; zero[2] = 0.f; zero[3] = 0.f;
  f32x4 acc[4][4];
  #pragma unroll
  for (int a = 0; a < 4; ++a)
    #pragma unroll
    for (int b = 0; b < 4; ++b) acc[a][b] = zero;

  // ---- prologue: stage fp8 tile 0 into buf 0 (8 loads in flight) ----
  #pragma unroll
  for (int it = 0; it < 4; ++it) {
    gl2lds16(aSrc8[it], &smem[0][dstOff[it]]);
    gl2lds16(bSrc8[it], &smem[0][16384 + dstOff[it]]);
  }

  int cur = 0;
  // ---- phase 1: fp8 MX spline, 64 K-steps ----
  for (int t = 0; t < 64; ++t) {
    const int nxt = cur ^ 1;
    if (t < 63) {                       // prefetch next fp8 tile
      const int kb = (t + 1) * BK8;
      #pragma unroll
      for (int it = 0; it < 4; ++it) {
        gl2lds16(aSrc8[it] + kb, &smem[nxt][dstOff[it]]);
        gl2lds16(bSrc8[it] + kb, &smem[nxt][16384 + dstOff[it]]);
      }
    } else {                            // chain: first bf16 tile
      #pragma unroll
      for (int it = 0; it < 4; ++it) {
        gl2lds16(aSrc16[it], &smem[nxt][dstOff[it]]);
        gl2lds16(bSrc16[it], &smem[nxt][16384 + dstOff[it]]);
      }
    }
    // wait tile t's 8 loads only; prefetch (8 newer) stays in flight
    asm volatile("s_waitcnt vmcnt(8)" ::: "memory");
    __builtin_amdgcn_s_barrier();
    asm volatile("" ::: "memory");
    const unsigned char* sp = smem[cur];
    union frag { int32x8 v; uint4 q[2]; };
    frag af[4], bfv[4];
    #pragma unroll
    for (int t4 = 0; t4 < 4; ++t4) {
      af[t4].q[0]  = *(const uint4*)(sp + a_off8[t4][0]);
      af[t4].q[1]  = *(const uint4*)(sp + a_off8[t4][1]);
      bfv[t4].q[0] = *(const uint4*)(sp + b_off8[t4][0]);
      bfv[t4].q[1] = *(const uint4*)(sp + b_off8[t4][1]);
    }
    __builtin_amdgcn_s_setprio(1);
    #pragma unroll
    for (int tm = 0; tm < 4; ++tm)
      #pragma unroll
      for (int tn = 0; tn < 4; ++tn)
        acc[tm][tn] = __builtin_amdgcn_mfma_scale_f32_16x16x128_f8f6f4(
            af[tm].v, bfv[tn].v, acc[tm][tn],
            0, 0, 0, 0x7F7F7F7F, 0, 0x7F7F7F7F);
    __builtin_amdgcn_s_setprio(0);
    asm volatile("" ::: "memory");
    __builtin_amdgcn_s_barrier();       // all readers of cur done
    asm volatile("" ::: "memory");
    cur = nxt;
  }

  // ---- phase 2: bf16 base, 16 K-steps, same structure, same acc ----
  for (int t = 0; t < 16; ++t) {
    const int nxt = cur ^ 1;
    if (t < 15) {
      const int ke = (t + 1) * BK;      // element offset
      #pragma unroll
      for (int it = 0; it < 4; ++it) {
        gl2lds16(aSrc16[it] + ke, &smem[nxt][dstOff[it]]);
        gl2lds16(bSrc16[it] + ke, &smem[nxt][16384 + dstOff[it]]);
      }
      asm volatile("s_waitcnt vmcnt(8)" ::: "memory");
    } else {
      asm volatile("s_waitcnt vmcnt(0)" ::: "memory");
    }
    __builtin_amdgcn_s_barrier();
    asm volatile("" ::: "memory");
    const unsigned char* sp = smem[cur];
    #pragma unroll
    for (int ks = 0; ks < 2; ++ks) {
      bf16x8 af[4], bfv[4];
      #pragma unroll
      for (int t4 = 0; t4 < 4; ++t4) af[t4]  = *(const bf16x8*)(sp + a_off16[ks][t4]);
      #pragma unroll
      for (int t4 = 0; t4 < 4; ++t4) bfv[t4] = *(const bf16x8*)(sp + b_off16[ks][t4]);
      __builtin_amdgcn_s_setprio(1);
      #pragma unroll
      for (int tm = 0; tm < 4; ++tm)
        #pragma unroll
        for (int tn = 0; tn < 4; ++tn)
          acc[tm][tn] = __builtin_amdgcn_mfma_f32_16x16x32_bf16(
              af[tm], bfv[tn], acc[tm][tn], 0, 0, 0);
      __builtin_amdgcn_s_setprio(0);
    }
    asm volatile("" ::: "memory");
    __builtin_amdgcn_s_barrier();
    asm volatile("" ::: "memory");
    cur = nxt;
  }

  // ---- epilogue: plain store ----
  #pragma unroll
  for (int tm = 0; tm < 4; ++tm) {
    const int row = r0 + wm * 64 + tm * 16 + quad * 4;
    #pragma unroll
    for (int tn = 0; tn < 4; ++tn) {
      const int col = c0 + wn * 64 + tn * 16 + l15;
      float* op = out + (size_t)row * OUT_F + col;
      #pragma unroll
      for (int r = 0; r < 4; ++r)
        op[(size_t)r * OUT_F] = acc[tm][tn][r];
    }
  }
}

// ---------- fallback path (ws too small): full-W bf16 prep + fused gemm ----------
__global__ __launch_bounds__(256)
void kan_prep_w_full(const float* __restrict__ sb, const float* __restrict__ sw,
                     const float* __restrict__ ss, __bf16* __restrict__ wbt) {
  const int t = threadIdx.x;
  if (blockIdx.x < 256) {
    __shared__ float tile[64][65];
    const int o0 = (blockIdx.x & 15) * 64, k0 = (blockIdx.x >> 4) * 64;
    const int r = t >> 4, c4 = (t & 15) * 4;
    #pragma unroll
    for (int it = 0; it < 4; ++it) {
      const int k = k0 + r + it * 16;
      float4 v = *(const float4*)(sb + (size_t)k * OUT_F + o0 + c4);
      tile[r + it * 16][c4 + 0] = v.x; tile[r + it * 16][c4 + 1] = v.y;
      tile[r + it * 16][c4 + 2] = v.z; tile[r + it * 16][c4 + 3] = v.w;
    }
    __syncthreads();
    #pragma unroll
    for (int it = 0; it < 4; ++it) {
      const int ol = r + it * 16;
      union { __bf16 h[4]; uint2 q; } s;
      #pragma unroll
      for (int e = 0; e < 4; ++e) s.h[e] = (__bf16)tile[c4 + e][ol];
      *(uint2*)(wbt + (size_t)(o0 + ol) * KTOT + k0 + c4) = s.q;
    }
  } else {
    const size_t e = ((size_t)(blockIdx.x - 256) * 256 + t) * 8;
    const int o = (int)(e >> 13);
    const int j = (int)(e & 8191);
    const int i = j >> 3;
    const float sc = ss[(size_t)i * OUT_F + o];
    float4 a = *(const float4*)(sw + e);
    float4 b = *(const float4*)(sw + e + 4);
    float vv[8] = {a.x, a.y, a.z, a.w, b.x, b.y, b.z, b.w};
    union { __bf16 h[8]; uint4 q; } s;
    #pragma unroll
    for (int g = 0; g < 8; ++g) s.h[g] = (__bf16)(vv[g] * sc);
    *(uint4*)(wbt + (size_t)o * KTOT + IN_F + j) = s.q;
  }
}

__global__ __launch_bounds__(256, 2)
void kan_gemm_fused(const float* __restrict__ x, const __bf16* __restrict__ wbt,
                    const float* __restrict__ grid, const float* __restrict__ sigma,
                    float* __restrict__ out) {
  __shared__ __bf16 As[BM * BK];
  __shared__ __bf16 Bs[BN * BK];
  __shared__ float  gLds[IN_F * GRID_N];
  const int tid = threadIdx.x;
  const int bx  = blockIdx.x;
  const int c0  = (bx & 7) * BN;
  const int r0  = (bx >> 3) * BM;
  for (int idx = tid; idx < IN_F * GRID_N / 4; idx += 256)
    ((float4*)gLds)[idx] = ((const float4*)grid)[idx];
  const float inv_sigma = 1.0f / sigma[0];
  const int lane = tid & 63, wave = tid >> 6;
  const int wm = wave & 1, wn = wave >> 1;
  const int quad = lane >> 4, l15 = lane & 15;
  f32x4 zero; zero[0] = 0.f; zero[1] = 0.f; zero[2] = 0.f; zero[3] = 0.f;
  f32x4 acc[4][4];
  #pragma unroll
  for (int a = 0; a < 4; ++a)
    #pragma unroll
    for (int b = 0; b < 4; ++b) acc[a][b] = zero;
  const int m = tid >> 1, half = tid & 1;
  const float* xrow = x + (size_t)(r0 + m) * IN_F;
  __syncthreads();
  for (int kb = 0; kb < KTOT; kb += BK) {
    union { __bf16 h[32]; uint4 q[4]; } av;
    if (kb < IN_F) {
      const float4* xp = (const float4*)(xrow + kb + half * 32);
      #pragma unroll
      for (int j4 = 0; j4 < 8; ++j4) {
        float4 v = xp[j4];
        float vv[4] = {v.x, v.y, v.z, v.w};
        #pragma unroll
        for (int e = 0; e < 4; ++e)
          av.h[j4 * 4 + e] = (__bf16)(vv[e] / (1.0f + __expf(-vv[e])));
      }
    } else {
      const int i0 = (kb - IN_F) >> 3;
      float4 xv = *(const float4*)(xrow + i0 + half * 4);
      float xs[4] = {xv.x, xv.y, xv.z, xv.w};
      #pragma unroll
      for (int ii = 0; ii < 4; ++ii) {
        const float u = xs[ii];
        const float* gp = &gLds[(i0 + half * 4 + ii) * GRID_N];
        #pragma unroll
        for (int g = 0; g < GRID_N; ++g) {
          float d = (u - gp[g]) * inv_sigma;
          av.h[ii * 8 + g] = (__bf16)__expf(-d * d);
        }
      }
    }
    __syncthreads();
    {
      uint4* dst = (uint4*)&As[m * BK + half * 32];
      #pragma unroll
      for (int qd = 0; qd < 4; ++qd) dst[qd] = av.q[qd];
    }
    #pragma unroll
    for (int it = 0; it < 4; ++it) {
      const int idx = it * 2048 + tid * 8;
      const int n = idx >> 6, k = idx & 63;
      gl2lds16(wbt + (size_t)(c0 + n) * KTOT + kb + k, &Bs[idx]);
    }
    __syncthreads();
    #pragma unroll
    for (int ks = 0; ks < 2; ++ks) {
      bf16x8 af[4], bfv[4];
      #pragma unroll
      for (int t4 = 0; t4 < 4; ++t4)
        af[t4] = *(const bf16x8*)&As[(wm * 64 + t4 * 16 + l15) * BK + ks * 32 + quad * 8];
      #pragma unroll
      for (int t4 = 0; t4 < 4; ++t4)
        bfv[t4] = *(const bf16x8*)&Bs[(wn * 64 + t4 * 16 + l15) * BK + ks * 32 + quad * 8];
      #pragma unroll
      for (int tm = 0; tm < 4; ++tm)
        #pragma unroll
        for (int tn = 0; tn < 4; ++tn)
          acc[tm][tn] = __builtin_amdgcn_mfma_f32_16x16x32_bf16(
              af[tm], bfv[tn], acc[tm][tn], 0, 0, 0);
    }
  }
  #pragma unroll
  for (int tm = 0; tm < 4; ++tm) {
    const int row = r0 + wm * 64 + tm * 16 + quad * 4;
    #pragma unroll
    for (int tn = 0; tn < 4; ++tn) {
      const int col = c0 + wn * 64 + tn * 16 + l15;
      float* op = out + (size_t)row * OUT_F + col;
      #pragma unroll
      for (int r = 0; r < 4; ++r)
        op[(size_t)r * OUT_F] = acc[tm][tn][r];
    }
  }
}

extern "C" void kernel_launch(void* const* d_in, const int* in_sizes, int n_in,
                              void* d_out, int out_size, void* d_ws, size_t ws_size,
                              hipStream_t stream) {
  const float* x     = (const float*)d_in[0];
  const float* sb    = (const float*)d_in[1];
  const float* sw    = (const float*)d_in[2];
  const float* ss    = (const float*)d_in[3];
  const float* grid  = (const float*)d_in[4];
  const float* sigma = (const float*)d_in[5];
  float* out = (float*)d_out;

  const size_t SBT_BYTES = (size_t)OUT_F * IN_F * 2;   //   2 MB (bf16)
  const size_t WS_BYTES  = (size_t)OUT_F * K2;         //  8.4 MB (fp8)
  const size_t A_BYTES   = (size_t)BATCH * K2;         // 67.1 MB (fp8)
  const size_t SBA_BYTES = (size_t)BATCH * IN_F * 2;   // 16.8 MB (bf16)

  if (ws_size >= SBT_BYTES + WS_BYTES + A_BYTES + SBA_BYTES) {
    __bf16*        sbT  = (__bf16*)d_ws;
    unsigned char* wbt8 = (unsigned char*)d_ws + SBT_BYTES;
    unsigned char* Ab8  = (unsigned char*)d_ws + SBT_BYTES + WS_BYTES;
    __bf16*        sbA  = (__bf16*)((char*)d_ws + SBT_BYTES + WS_BYTES + A_BYTES);
    kan_mix<<<dim3(512 + BATCH), dim3(256), 0, stream>>>(
        x, sb, sw, ss, grid, sigma, sbT, wbt8, Ab8, sbA);
    kan_gemm_all<<<dim3((BATCH / BM) * (OUT_F / BN)), dim3(256), 0, stream>>>(
        Ab8, wbt8, sbA, sbT, out);
  } else {
    __bf16* wbt = (__bf16*)d_ws;   // 18.9 MB
    kan_prep_w_full<<<dim3(4352), dim3(256), 0, stream>>>(sb, sw, ss, wbt);
    kan_gemm_fused<<<dim3((BATCH / BM) * (OUT_F / BN)), dim3(256), 0, stream>>>(
        x, wbt, grid, sigma, out);
  }
}